// Round 7
// baseline (55.235 us; speedup 1.0000x reference)
//
#include <hip/hip_runtime.h>
#include <hip/hip_bf16.h>

#define NN 4096
#define FF 512
#define RR 64
#define HH 8
#define HR (HH * RR)     // 512
#define CAP 128
#define ATT_STRIDE 144   // group offset 16 mod 32 -> 2-way (free) in softmax

typedef short bf16x8 __attribute__((ext_vector_type(8)));
typedef float f32x4 __attribute__((ext_vector_type(4)));

__device__ __forceinline__ unsigned short f2bf(float f) {
  __hip_bfloat16 h = __float2bfloat16(f);   // RNE
  return *reinterpret_cast<unsigned short*>(&h);
}
__device__ __forceinline__ float bf2f(unsigned short u) {
  union { unsigned u32; float f; } cv;
  cv.u32 = ((unsigned)u) << 16;
  return cv.f;
}

// ---------------------------------------------------------------------------
// K0: Xb[n][f] = bf16(X[n][f]);  BbT[(h*64+r)][f] = bf16(W[h][f][r])
// ---------------------------------------------------------------------------
__global__ __launch_bounds__(256) void k_convert(
    const float* __restrict__ X, const float* __restrict__ W,
    unsigned short* __restrict__ Xb, unsigned short* __restrict__ BbT)
{
  const int t = blockIdx.x * 256 + threadIdx.x;
  if (t < 524288) {
    const float4 v = reinterpret_cast<const float4*>(X)[t];
    ushort4 u;
    u.x = f2bf(v.x); u.y = f2bf(v.y); u.z = f2bf(v.z); u.w = f2bf(v.w);
    reinterpret_cast<ushort4*>(Xb)[t] = u;
  } else {
    const int o = t - 524288;          // 0..262143
    const int n = o >> 9;              // (h*64+r)
    const int f = o & 511;
    const int h = n >> 6, r = n & 63;
    BbT[(size_t)n * FF + f] = f2bf(W[(size_t)h * FF * RR + (size_t)f * RR + r]);
  }
}

// ---------------------------------------------------------------------------
// K1: hiddenT[m][n] = sum_k Xb[m][k] * BbT[n][k]   (M=4096, N=512, K=512)
// 64x64 tile, 256 thr = 4 waves, wave (wr,wc) owns 32x32 via 2x2 16x16x32 MFMA.
// ---------------------------------------------------------------------------
__global__ __launch_bounds__(256) void k_gemm_hidden(
    const unsigned short* __restrict__ Xb,
    const unsigned short* __restrict__ BbT,
    unsigned short* __restrict__ hiddenT)
{
  const int row0 = blockIdx.x * 64;   // M
  const int n0 = blockIdx.y * 64;     // N
  __shared__ unsigned short Als[64 * 32];  // [m][k], row stride 32 elts (64 B)
  __shared__ unsigned short Bls[64 * 32];  // [n][k]
  const int tid = threadIdx.x;
  const int l = tid & 63;
  const int wid = tid >> 6;
  const int wr = wid >> 1, wc = wid & 1;

  f32x4 acc[2][2];
#pragma unroll
  for (int a = 0; a < 2; ++a)
#pragma unroll
    for (int b = 0; b < 2; ++b) acc[a][b] = (f32x4){0.f, 0.f, 0.f, 0.f};

  const int srow = tid >> 2;           // 0..63
  const int skel = (tid & 3) * 8;      // k element 0,8,16,24

  for (int k0 = 0; k0 < FF; k0 += 32) {
    const int4 av = *reinterpret_cast<const int4*>(
        &Xb[(size_t)(row0 + srow) * FF + k0 + skel]);
    const int4 bv = *reinterpret_cast<const int4*>(
        &BbT[(size_t)(n0 + srow) * FF + k0 + skel]);
    __syncthreads();
    *reinterpret_cast<int4*>(&Als[tid * 8]) = av;
    *reinterpret_cast<int4*>(&Bls[tid * 8]) = bv;
    __syncthreads();

    const int ka = (l >> 4) * 8;
    const bf16x8 a0 = *reinterpret_cast<const bf16x8*>(&Als[(32 * wr + 0  + (l & 15)) * 32 + ka]);
    const bf16x8 a1 = *reinterpret_cast<const bf16x8*>(&Als[(32 * wr + 16 + (l & 15)) * 32 + ka]);
    const bf16x8 b0 = *reinterpret_cast<const bf16x8*>(&Bls[(32 * wc + 0  + (l & 15)) * 32 + ka]);
    const bf16x8 b1 = *reinterpret_cast<const bf16x8*>(&Bls[(32 * wc + 16 + (l & 15)) * 32 + ka]);
    acc[0][0] = __builtin_amdgcn_mfma_f32_16x16x32_bf16(a0, b0, acc[0][0], 0, 0, 0);
    acc[0][1] = __builtin_amdgcn_mfma_f32_16x16x32_bf16(a0, b1, acc[0][1], 0, 0, 0);
    acc[1][0] = __builtin_amdgcn_mfma_f32_16x16x32_bf16(a1, b0, acc[1][0], 0, 0, 0);
    acc[1][1] = __builtin_amdgcn_mfma_f32_16x16x32_bf16(a1, b1, acc[1][1], 0, 0, 0);
  }

  // epilogue: C/D layout col=l&15, row=(l>>4)*4+j  (m89-verified)
#pragma unroll
  for (int mi = 0; mi < 2; ++mi)
#pragma unroll
    for (int ni = 0; ni < 2; ++ni)
#pragma unroll
      for (int j = 0; j < 4; ++j) {
        const int rowg = row0 + 32 * wr + 16 * mi + ((l >> 4) << 2) + j;
        const int colg = n0 + 32 * wc + 16 * ni + (l & 15);
        hiddenT[(size_t)rowg * HR + colg] = f2bf(acc[mi][ni][j]);
      }
}

// ---------------------------------------------------------------------------
// K2: a_src[h][n] = hiddenT[n][h*64+:64] . sa[h][0:64];  a_dstT[n][h] likewise
// ---------------------------------------------------------------------------
__global__ __launch_bounds__(256) void k_src_dst(
    const unsigned short* __restrict__ hiddenT,
    const float* __restrict__ sa,
    float* __restrict__ a_src,
    float* __restrict__ a_dstT)
{
  const int idx = blockIdx.x * 256 + threadIdx.x;  // 0..32767
  const int h = idx & 7;
  const int n = idx >> 3;
  const unsigned short* hp = hiddenT + (size_t)n * HR + h * RR;
  const float* ss = sa + (size_t)h * 2 * RR;
  const float* sd = ss + RR;
  float s = 0.f, d = 0.f;
#pragma unroll
  for (int v = 0; v < 16; ++v) {
    const ushort4 u = reinterpret_cast<const ushort4*>(hp)[v];
    const float4 sv = reinterpret_cast<const float4*>(ss)[v];
    const float4 dv = reinterpret_cast<const float4*>(sd)[v];
    const float x0 = bf2f(u.x), x1 = bf2f(u.y), x2 = bf2f(u.z), x3 = bf2f(u.w);
    s += x0 * sv.x + x1 * sv.y + x2 * sv.z + x3 * sv.w;
    d += x0 * dv.x + x1 * dv.y + x2 * dv.z + x3 * dv.w;
  }
  a_src[(size_t)h * NN + n] = s;
  a_dstT[(size_t)n * HH + h] = d;
}

__device__ __forceinline__ unsigned nib4(const float4 v) {
  unsigned m = 0;
  if (v.x != 0.f) m |= 1u;
  if (v.y != 0.f) m |= 2u;
  if (v.z != 0.f) m |= 4u;
  if (v.w != 0.f) m |= 8u;
  return m;
}

// ---------------------------------------------------------------------------
// K3a: PURE STREAMING compaction. One wave per row, zero barriers.
// Writes colsG[row][CAP] (lane-major deterministic order) + cnts[row].
// ---------------------------------------------------------------------------
__global__ __launch_bounds__(256) void k_compact(
    const float* __restrict__ adj,
    int* __restrict__ colsG,
    int* __restrict__ cnts)
{
  const int tid = threadIdx.x;
  const int lane = tid & 63;
  const int row = blockIdx.x * 4 + (tid >> 6);
  const float* arow = adj + (size_t)row * NN;

  unsigned long long pm = 0;
  {
    float4 buf[8];
#pragma unroll
    for (int c = 0; c < 8; ++c)
      buf[c] = *reinterpret_cast<const float4*>(&arow[c * 256 + (lane << 2)]);
#pragma unroll
    for (int c = 0; c < 8; ++c)
      pm |= (unsigned long long)nib4(buf[c]) << (4 * c);
#pragma unroll
    for (int c = 0; c < 8; ++c)
      buf[c] = *reinterpret_cast<const float4*>(&arow[(c + 8) * 256 + (lane << 2)]);
#pragma unroll
    for (int c = 0; c < 8; ++c)
      pm |= (unsigned long long)nib4(buf[c]) << (4 * c + 32);
  }
  const int cnt = __popcll(pm);

  int pfx = cnt;
#pragma unroll
  for (int off = 1; off < 64; off <<= 1) {
    const int o = __shfl_up(pfx, off);
    if (lane >= off) pfx += o;
  }

  int pos = pfx - cnt;
  unsigned long long m = pm;
  int* cg = colsG + (size_t)row * CAP;
  while (m) {
    const int b = (int)__builtin_ctzll(m);
    m &= m - 1;
    if (pos < CAP) cg[pos] = ((b >> 2) << 8) + (lane << 2) + (b & 3);
    ++pos;
  }
  if (lane == 63) cnts[row] = pfx < CAP ? pfx : CAP;
}

// ---------------------------------------------------------------------------
// K3b: one 128-thread block per row; NO adjacency read.
// scores -> softmax -> sparse aggregation.
// ---------------------------------------------------------------------------
__global__ __launch_bounds__(128) void k_gat_row(
    const int* __restrict__ colsG,
    const int* __restrict__ cnts,
    const float* __restrict__ bias,
    const float* __restrict__ a_src,
    const float* __restrict__ a_dstT,
    const unsigned short* __restrict__ hiddenT,
    float* __restrict__ out)
{
  const int i = blockIdx.x;
  const int tid = threadIdx.x;

  __shared__ __align__(16) float att[HH][ATT_STRIDE];
  __shared__ int cols[CAP];

  const int count = cnts[i];
  const float* brow = bias + (size_t)i * NN;

  float asrc[HH];
#pragma unroll
  for (int h = 0; h < HH; ++h) asrc[h] = a_src[(size_t)h * NN + i];

  // ---- scores for all 8 heads (count <= 128 -> 1 iteration) ----
  if (tid < count) {
    const int c = colsG[(size_t)i * CAP + tid];
    cols[tid] = c;
    const float b = 0.01f * brow[c];
    const float4 d0 = *reinterpret_cast<const float4*>(&a_dstT[(size_t)c * HH]);
    const float4 d1 = *reinterpret_cast<const float4*>(&a_dstT[(size_t)c * HH + 4]);
    float s;
    s = asrc[0] + d0.x + b; att[0][tid] = (s >= 0.f) ? s : 0.2f * s;
    s = asrc[1] + d0.y + b; att[1][tid] = (s >= 0.f) ? s : 0.2f * s;
    s = asrc[2] + d0.z + b; att[2][tid] = (s >= 0.f) ? s : 0.2f * s;
    s = asrc[3] + d0.w + b; att[3][tid] = (s >= 0.f) ? s : 0.2f * s;
    s = asrc[4] + d1.x + b; att[4][tid] = (s >= 0.f) ? s : 0.2f * s;
    s = asrc[5] + d1.y + b; att[5][tid] = (s >= 0.f) ? s : 0.2f * s;
    s = asrc[6] + d1.z + b; att[6][tid] = (s >= 0.f) ? s : 0.2f * s;
    s = asrc[7] + d1.w + b; att[7][tid] = (s >= 0.f) ? s : 0.2f * s;
  }
  __syncthreads();

  // ---- softmax; 16-lane group g = tid>>4 owns head g ----
  {
    const int g = tid >> 4;
    const int l16 = tid & 15;
    float* arow_h = att[g];
    float m = -3.0e38f;
    for (int t = l16; t < count; t += 16) m = fmaxf(m, arow_h[t]);
#pragma unroll
    for (int o = 8; o >= 1; o >>= 1) m = fmaxf(m, __shfl_xor(m, o));
    float ssum = 0.f;
    for (int t = l16; t < count; t += 16) {
      const float e = expf(arow_h[t] - m);
      arow_h[t] = e;
      ssum += e;
    }
#pragma unroll
    for (int o = 8; o >= 1; o >>= 1) ssum += __shfl_xor(ssum, o);
    const float inv = 1.0f / ssum;
    for (int t = l16; t < count; t += 16) arow_h[t] *= inv;
  }
  __syncthreads();

  // ---- aggregation: thread owns 4 outputs at o0 = tid*4; h = tid>>4 ----
  {
    const int o0 = tid << 2;
    const float* attrow = att[tid >> 4];
    const unsigned short* hb = hiddenT + o0;
    float4 acc = make_float4(0.f, 0.f, 0.f, 0.f);
    int t = 0;
    for (; t + 4 <= count; t += 4) {
      const int4 c4 = *reinterpret_cast<const int4*>(&cols[t]);
      const float4 a4 = *reinterpret_cast<const float4*>(&attrow[t]);
#pragma unroll
      for (int j = 0; j < 4; ++j) {
        const int c = (j == 0) ? c4.x : (j == 1) ? c4.y : (j == 2) ? c4.z : c4.w;
        const float a = (j == 0) ? a4.x : (j == 1) ? a4.y : (j == 2) ? a4.z : a4.w;
        const ushort4 u = *reinterpret_cast<const ushort4*>(hb + (size_t)c * HR);
        acc.x += a * bf2f(u.x); acc.y += a * bf2f(u.y);
        acc.z += a * bf2f(u.z); acc.w += a * bf2f(u.w);
      }
    }
    for (; t < count; ++t) {
      const int c = cols[t];
      const float a = attrow[t];
      const ushort4 u = *reinterpret_cast<const ushort4*>(hb + (size_t)c * HR);
      acc.x += a * bf2f(u.x); acc.y += a * bf2f(u.y);
      acc.z += a * bf2f(u.z); acc.w += a * bf2f(u.w);
    }
    *reinterpret_cast<float4*>(&out[(size_t)i * HR + o0]) = acc;
  }
}

extern "C" void kernel_launch(void* const* d_in, const int* in_sizes, int n_in,
                              void* d_out, int out_size, void* d_ws, size_t ws_size,
                              hipStream_t stream) {
  const float* X    = (const float*)d_in[0];   // [N,F]
  const float* adj  = (const float*)d_in[1];   // [N,N]
  const float* W    = (const float*)d_in[2];   // [H,F,R]
  const float* sa   = (const float*)d_in[3];   // [H,2R]
  const float* bias = (const float*)d_in[4];   // [N,N]
  float* out = (float*)d_out;                  // [N, H*R]

  unsigned short* hiddenT = (unsigned short*)d_ws;        // [N][512] bf16, 4 MB
  unsigned short* Xb  = hiddenT + (size_t)NN * HR;        // [N][512] bf16, 4 MB
  unsigned short* BbT = Xb + (size_t)NN * FF;             // [512][512] bf16, 512 KB
  float* a_src  = (float*)(BbT + (size_t)HR * FF);        // [H][N], 128 KB
  float* a_dstT = a_src + (size_t)HH * NN;                // [N][H], 128 KB
  int* cnts     = (int*)(a_dstT + (size_t)NN * HH);       // [N], 16 KB
  int* colsG    = (int*)Xb;  // reuses Xb region (dead after k_gemm_hidden), 2 MB

  k_convert<<<dim3(3072), 256, 0, stream>>>(X, W, Xb, BbT);
  k_gemm_hidden<<<dim3(NN / 64, HR / 64), 256, 0, stream>>>(Xb, BbT, hiddenT);
  k_src_dst<<<dim3(128), 256, 0, stream>>>(hiddenT, sa, a_src, a_dstT);
  k_compact<<<dim3(NN / 4), 256, 0, stream>>>(adj, colsG, cnts);
  k_gat_row<<<dim3(NN), 128, 0, stream>>>(colsG, cnts, bias, a_src, a_dstT, hiddenT, out);
}

// Round 8
// 48.198 us; speedup vs baseline: 1.1460x; 1.1460x over previous
//
#include <hip/hip_runtime.h>
#include <hip/hip_bf16.h>

#define NN 4096
#define FF 512
#define RR 64
#define HH 8
#define HR (HH * RR)     // 512
#define CAP 128
#define ATT_STRIDE 144

typedef short bf16x8 __attribute__((ext_vector_type(8)));
typedef float f32x4 __attribute__((ext_vector_type(4)));

__device__ __forceinline__ unsigned short f2bf(float f) {
  __hip_bfloat16 h = __float2bfloat16(f);   // RNE
  return *reinterpret_cast<unsigned short*>(&h);
}
__device__ __forceinline__ float bf2f(unsigned short u) {
  union { unsigned u32; float f; } cv;
  cv.u32 = ((unsigned)u) << 16;
  return cv.f;
}
__device__ __forceinline__ unsigned nib4(const float4 v) {
  unsigned m = 0;
  if (v.x != 0.f) m |= 1u;
  if (v.y != 0.f) m |= 2u;
  if (v.z != 0.f) m |= 4u;
  if (v.w != 0.f) m |= 8u;
  return m;
}

// ---------------------------------------------------------------------------
// K_A: fused streaming. blocks [0,1024): adjacency compaction (4 rows/block);
// [1024,3072): X fp32->bf16; [3072,3136): W transpose-convert via LDS tile.
// ---------------------------------------------------------------------------
__global__ __launch_bounds__(256) void k_stream(
    const float* __restrict__ X, const float* __restrict__ W,
    const float* __restrict__ adj,
    unsigned short* __restrict__ Xb, unsigned short* __restrict__ BbT,
    int* __restrict__ colsG, int* __restrict__ cnts)
{
  __shared__ unsigned short wt[64][68];   // [r][f'] bf16, padded
  const int b = blockIdx.x;
  const int tid = threadIdx.x;

  if (b < 1024) {
    // ---- adjacency compaction: one wave per row, zero barriers ----
    const int lane = tid & 63;
    const int row = b * 4 + (tid >> 6);
    const float* arow = adj + (size_t)row * NN;
    unsigned long long pm = 0;
    {
      float4 buf[8];
#pragma unroll
      for (int c = 0; c < 8; ++c)
        buf[c] = *reinterpret_cast<const float4*>(&arow[c * 256 + (lane << 2)]);
#pragma unroll
      for (int c = 0; c < 8; ++c)
        pm |= (unsigned long long)nib4(buf[c]) << (4 * c);
#pragma unroll
      for (int c = 0; c < 8; ++c)
        buf[c] = *reinterpret_cast<const float4*>(&arow[(c + 8) * 256 + (lane << 2)]);
#pragma unroll
      for (int c = 0; c < 8; ++c)
        pm |= (unsigned long long)nib4(buf[c]) << (4 * c + 32);
    }
    const int cnt = __popcll(pm);
    int pfx = cnt;
#pragma unroll
    for (int off = 1; off < 64; off <<= 1) {
      const int o = __shfl_up(pfx, off);
      if (lane >= off) pfx += o;
    }
    int pos = pfx - cnt;
    unsigned long long m = pm;
    int* cg = colsG + (size_t)row * CAP;
    while (m) {
      const int bit = (int)__builtin_ctzll(m);
      m &= m - 1;
      if (pos < CAP) cg[pos] = ((bit >> 2) << 8) + (lane << 2) + (bit & 3);
      ++pos;
    }
    if (lane == 63) cnts[row] = pfx < CAP ? pfx : CAP;
  } else if (b < 3072) {
    // ---- X convert: float4 -> ushort4 ----
    const int t = (b - 1024) * 256 + tid;   // 0..524287
    const float4 v = reinterpret_cast<const float4*>(X)[t];
    ushort4 u;
    u.x = f2bf(v.x); u.y = f2bf(v.y); u.z = f2bf(v.z); u.w = f2bf(v.w);
    reinterpret_cast<ushort4*>(Xb)[t] = u;
  } else {
    // ---- W transpose-convert: block handles head h, f-tile ft (64f x 64r) ----
    const int b2 = b - 3072;        // 0..63
    const int h = b2 >> 3;
    const int f0 = (b2 & 7) << 6;
    const int fr = tid >> 2;        // 0..63
    const int rq = (tid & 3) << 4;  // 0,16,32,48
    const float* wp = W + (size_t)h * FF * RR + (size_t)(f0 + fr) * RR + rq;
#pragma unroll
    for (int v = 0; v < 4; ++v) {
      const float4 x = *reinterpret_cast<const float4*>(wp + v * 4);
      wt[rq + v * 4 + 0][fr] = f2bf(x.x);
      wt[rq + v * 4 + 1][fr] = f2bf(x.y);
      wt[rq + v * 4 + 2][fr] = f2bf(x.z);
      wt[rq + v * 4 + 3][fr] = f2bf(x.w);
    }
    __syncthreads();
    // write BbT[(h*64+r)][f0 + f'] : row r = tid>>2, f' chunk = (tid&3)*16
    const int r = tid >> 2;
    unsigned short* op = BbT + (size_t)(h * 64 + r) * FF + f0 + ((tid & 3) << 4);
    int4 w0, w1;
    w0 = *reinterpret_cast<const int4*>(&wt[r][(tid & 3) << 4]);
    w1 = *reinterpret_cast<const int4*>(&wt[r][((tid & 3) << 4) + 8]);
    *reinterpret_cast<int4*>(op) = w0;
    *reinterpret_cast<int4*>(op + 8) = w1;
  }
}

// ---------------------------------------------------------------------------
// K_B: hiddenT[m][n] = sum_k Xb[m][k] * BbT[n][k]  (M=4096, N=512, K=512)
// + fused epilogue computing a_src / a_dstT from fp32 accumulators.
// blockIdx.y == head h. 64x64 tile, 4 waves, 2x2 16x16x32 MFMA per wave.
// ---------------------------------------------------------------------------
__global__ __launch_bounds__(256) void k_gemm_hidden(
    const unsigned short* __restrict__ Xb,
    const unsigned short* __restrict__ BbT,
    const float* __restrict__ sa,
    unsigned short* __restrict__ hiddenT,
    float* __restrict__ a_src,
    float* __restrict__ a_dstT)
{
  const int row0 = blockIdx.x * 64;
  const int h = blockIdx.y;
  const int n0 = h * 64;
  __shared__ unsigned short Als[64 * 32];
  __shared__ unsigned short Bls[64 * 32];
  __shared__ float redS[64][2];
  __shared__ float redD[64][2];
  const int tid = threadIdx.x;
  const int l = tid & 63;
  const int wid = tid >> 6;
  const int wr = wid >> 1, wc = wid & 1;

  f32x4 acc[2][2];
#pragma unroll
  for (int a = 0; a < 2; ++a)
#pragma unroll
    for (int bb = 0; bb < 2; ++bb) acc[a][bb] = (f32x4){0.f, 0.f, 0.f, 0.f};

  const int srow = tid >> 2;
  const int skel = (tid & 3) * 8;

  for (int k0 = 0; k0 < FF; k0 += 32) {
    const int4 av = *reinterpret_cast<const int4*>(
        &Xb[(size_t)(row0 + srow) * FF + k0 + skel]);
    const int4 bv = *reinterpret_cast<const int4*>(
        &BbT[(size_t)(n0 + srow) * FF + k0 + skel]);
    __syncthreads();
    *reinterpret_cast<int4*>(&Als[tid * 8]) = av;
    *reinterpret_cast<int4*>(&Bls[tid * 8]) = bv;
    __syncthreads();

    const int ka = (l >> 4) * 8;
    const bf16x8 a0 = *reinterpret_cast<const bf16x8*>(&Als[(32 * wr + 0  + (l & 15)) * 32 + ka]);
    const bf16x8 a1 = *reinterpret_cast<const bf16x8*>(&Als[(32 * wr + 16 + (l & 15)) * 32 + ka]);
    const bf16x8 b0 = *reinterpret_cast<const bf16x8*>(&Bls[(32 * wc + 0  + (l & 15)) * 32 + ka]);
    const bf16x8 b1 = *reinterpret_cast<const bf16x8*>(&Bls[(32 * wc + 16 + (l & 15)) * 32 + ka]);
    acc[0][0] = __builtin_amdgcn_mfma_f32_16x16x32_bf16(a0, b0, acc[0][0], 0, 0, 0);
    acc[0][1] = __builtin_amdgcn_mfma_f32_16x16x32_bf16(a0, b1, acc[0][1], 0, 0, 0);
    acc[1][0] = __builtin_amdgcn_mfma_f32_16x16x32_bf16(a1, b0, acc[1][0], 0, 0, 0);
    acc[1][1] = __builtin_amdgcn_mfma_f32_16x16x32_bf16(a1, b1, acc[1][1], 0, 0, 0);
  }

  const int lg = l >> 4;    // 0..3
  const int lc = l & 15;

  // ---- write bf16 hiddenT ----
#pragma unroll
  for (int mi = 0; mi < 2; ++mi)
#pragma unroll
    for (int ni = 0; ni < 2; ++ni)
#pragma unroll
      for (int j = 0; j < 4; ++j) {
        const int rowg = row0 + 32 * wr + 16 * mi + (lg << 2) + j;
        const int colg = n0 + 32 * wc + 16 * ni + lc;
        hiddenT[(size_t)rowg * HR + colg] = f2bf(acc[mi][ni][j]);
      }

  // ---- fused a_src / a_dstT from fp32 acc ----
  float sS[2], sD[2];
#pragma unroll
  for (int ni = 0; ni < 2; ++ni) {
    const int col = 32 * wc + 16 * ni + lc;
    sS[ni] = sa[(size_t)h * 2 * RR + col];
    sD[ni] = sa[(size_t)h * 2 * RR + RR + col];
  }
#pragma unroll
  for (int mi = 0; mi < 2; ++mi)
#pragma unroll
    for (int j = 0; j < 4; ++j) {
      float ps = acc[mi][0][j] * sS[0] + acc[mi][1][j] * sS[1];
      float pd = acc[mi][0][j] * sD[0] + acc[mi][1][j] * sD[1];
#pragma unroll
      for (int off = 8; off >= 1; off >>= 1) {
        ps += __shfl_xor(ps, off);
        pd += __shfl_xor(pd, off);
      }
      if (lc == 0) {
        const int rl = 32 * wr + 16 * mi + (lg << 2) + j;
        redS[rl][wc] = ps;
        redD[rl][wc] = pd;
      }
    }
  __syncthreads();
  if (tid < 64) {
    a_src[(size_t)h * NN + row0 + tid] = redS[tid][0] + redS[tid][1];
    a_dstT[(size_t)(row0 + tid) * HH + h] = redD[tid][0] + redD[tid][1];
  }
}

// ---------------------------------------------------------------------------
// K_C: one 256-thread block per row; no adjacency read.
// scores -> softmax -> aggregation split across 2 thread groups + LDS reduce.
// ---------------------------------------------------------------------------
__global__ __launch_bounds__(256) void k_gat_row(
    const int* __restrict__ colsG,
    const int* __restrict__ cnts,
    const float* __restrict__ bias,
    const float* __restrict__ a_src,
    const float* __restrict__ a_dstT,
    const unsigned short* __restrict__ hiddenT,
    float* __restrict__ out)
{
  const int i = blockIdx.x;
  const int tid = threadIdx.x;

  __shared__ __align__(16) float att[HH][ATT_STRIDE];
  __shared__ int cols[CAP];
  __shared__ __align__(16) float accred[2][HR];

  const int count = cnts[i];
  const float* brow = bias + (size_t)i * NN;

  float asrc[HH];
#pragma unroll
  for (int h = 0; h < HH; ++h) asrc[h] = a_src[(size_t)h * NN + i];

  // ---- scores (count <= 128 -> threads 0..count-1, one pass) ----
  if (tid < count) {
    const int c = colsG[(size_t)i * CAP + tid];
    cols[tid] = c;
    const float b = 0.01f * brow[c];
    const float4 d0 = *reinterpret_cast<const float4*>(&a_dstT[(size_t)c * HH]);
    const float4 d1 = *reinterpret_cast<const float4*>(&a_dstT[(size_t)c * HH + 4]);
    float s;
    s = asrc[0] + d0.x + b; att[0][tid] = (s >= 0.f) ? s : 0.2f * s;
    s = asrc[1] + d0.y + b; att[1][tid] = (s >= 0.f) ? s : 0.2f * s;
    s = asrc[2] + d0.z + b; att[2][tid] = (s >= 0.f) ? s : 0.2f * s;
    s = asrc[3] + d0.w + b; att[3][tid] = (s >= 0.f) ? s : 0.2f * s;
    s = asrc[4] + d1.x + b; att[4][tid] = (s >= 0.f) ? s : 0.2f * s;
    s = asrc[5] + d1.y + b; att[5][tid] = (s >= 0.f) ? s : 0.2f * s;
    s = asrc[6] + d1.z + b; att[6][tid] = (s >= 0.f) ? s : 0.2f * s;
    s = asrc[7] + d1.w + b; att[7][tid] = (s >= 0.f) ? s : 0.2f * s;
  }
  __syncthreads();

  // ---- softmax: 32-lane group g = tid>>5 owns head g ----
  {
    const int g = tid >> 5;
    const int l = tid & 31;
    float* arow_h = att[g];
    float m = -3.0e38f;
    for (int t = l; t < count; t += 32) m = fmaxf(m, arow_h[t]);
#pragma unroll
    for (int o = 16; o >= 1; o >>= 1) m = fmaxf(m, __shfl_xor(m, o));
    float ssum = 0.f;
    for (int t = l; t < count; t += 32) {
      const float e = expf(arow_h[t] - m);
      arow_h[t] = e;
      ssum += e;
    }
#pragma unroll
    for (int o = 16; o >= 1; o >>= 1) ssum += __shfl_xor(ssum, o);
    const float inv = 1.0f / ssum;
    for (int t = l; t < count; t += 32) arow_h[t] *= inv;
  }
  __syncthreads();

  // ---- aggregation: group g2 = tid>>7 takes its half of the neighbors;
  //      thread owns 4 outputs at o0 = (tid&127)*4; LDS reduce after. ----
  {
    const int g2 = tid >> 7;
    const int o0 = (tid & 127) << 2;
    const float* attrow = att[o0 >> 6];
    const unsigned short* hb = hiddenT + o0;
    const int half = (count + 1) >> 1;
    const int t0 = g2 * half;
    const int t1 = (g2 == 0) ? half : count;
    float4 acc = make_float4(0.f, 0.f, 0.f, 0.f);
    int t = t0;
    for (; t + 2 <= t1; t += 2) {
      const int ca = cols[t], cb = cols[t + 1];
      const float aa = attrow[t], ab = attrow[t + 1];
      const ushort4 ua = *reinterpret_cast<const ushort4*>(hb + (size_t)ca * HR);
      const ushort4 ub = *reinterpret_cast<const ushort4*>(hb + (size_t)cb * HR);
      acc.x += aa * bf2f(ua.x) + ab * bf2f(ub.x);
      acc.y += aa * bf2f(ua.y) + ab * bf2f(ub.y);
      acc.z += aa * bf2f(ua.z) + ab * bf2f(ub.z);
      acc.w += aa * bf2f(ua.w) + ab * bf2f(ub.w);
    }
    if (t < t1) {
      const int c = cols[t];
      const float a = attrow[t];
      const ushort4 u = *reinterpret_cast<const ushort4*>(hb + (size_t)c * HR);
      acc.x += a * bf2f(u.x); acc.y += a * bf2f(u.y);
      acc.z += a * bf2f(u.z); acc.w += a * bf2f(u.w);
    }
    *reinterpret_cast<float4*>(&accred[g2][o0]) = acc;
  }
  __syncthreads();
  {
    const int o = tid << 1;
    const float2 r = make_float2(accred[0][o] + accred[1][o],
                                 accred[0][o + 1] + accred[1][o + 1]);
    *reinterpret_cast<float2*>(&out[(size_t)i * HR + o]) = r;
  }
}

extern "C" void kernel_launch(void* const* d_in, const int* in_sizes, int n_in,
                              void* d_out, int out_size, void* d_ws, size_t ws_size,
                              hipStream_t stream) {
  const float* X    = (const float*)d_in[0];   // [N,F]
  const float* adj  = (const float*)d_in[1];   // [N,N]
  const float* W    = (const float*)d_in[2];   // [H,F,R]
  const float* sa   = (const float*)d_in[3];   // [H,2R]
  const float* bias = (const float*)d_in[4];   // [N,N]
  float* out = (float*)d_out;                  // [N, H*R]

  unsigned short* hiddenT = (unsigned short*)d_ws;        // [N][512] bf16, 4 MB
  unsigned short* Xb  = hiddenT + (size_t)NN * HR;        // [N][512] bf16, 4 MB
  unsigned short* BbT = Xb + (size_t)NN * FF;             // [512][512] bf16, 512 KB
  float* a_src  = (float*)(BbT + (size_t)HR * FF);        // [H][N], 128 KB
  float* a_dstT = a_src + (size_t)HH * NN;                // [N][H], 128 KB
  int* cnts     = (int*)(a_dstT + (size_t)NN * HH);       // [N], 16 KB
  int* colsG    = cnts + NN;                              // [N][CAP], 2 MB

  k_stream<<<dim3(3136), 256, 0, stream>>>(X, W, adj, Xb, BbT, colsG, cnts);
  k_gemm_hidden<<<dim3(NN / 64, HH), 256, 0, stream>>>(Xb, BbT, sa, hiddenT, a_src, a_dstT);
  k_gat_row<<<dim3(NN), 256, 0, stream>>>(colsG, cnts, bias, a_src, a_dstT, hiddenT, out);
}

// Round 9
// 47.000 us; speedup vs baseline: 1.1752x; 1.0255x over previous
//
#include <hip/hip_runtime.h>
#include <hip/hip_bf16.h>

#define NN 4096
#define FF 512
#define RR 64
#define HH 8
#define HR (HH * RR)     // 512
#define CAP 128
#define ATT_STRIDE 144

typedef short bf16x8 __attribute__((ext_vector_type(8)));
typedef float f32x4 __attribute__((ext_vector_type(4)));

__device__ __forceinline__ unsigned short f2bf(float f) {
  __hip_bfloat16 h = __float2bfloat16(f);   // RNE
  return *reinterpret_cast<unsigned short*>(&h);
}
__device__ __forceinline__ float bf2f(unsigned short u) {
  union { unsigned u32; float f; } cv;
  cv.u32 = ((unsigned)u) << 16;
  return cv.f;
}
__device__ __forceinline__ unsigned nib4(const float4 v) {
  unsigned m = 0;
  if (v.x != 0.f) m |= 1u;
  if (v.y != 0.f) m |= 2u;
  if (v.z != 0.f) m |= 4u;
  if (v.w != 0.f) m |= 8u;
  return m;
}

// ---------------------------------------------------------------------------
// K_A: fused streaming. blocks [0,1024): adjacency compaction (4 rows/block,
// tail zero-padded to CAP); [1024,3072): X fp32->bf16; [3072,3136): W
// transpose-convert via LDS tile.
// ---------------------------------------------------------------------------
__global__ __launch_bounds__(256) void k_stream(
    const float* __restrict__ X, const float* __restrict__ W,
    const float* __restrict__ adj,
    unsigned short* __restrict__ Xb, unsigned short* __restrict__ BbT,
    int* __restrict__ colsG, int* __restrict__ cnts)
{
  __shared__ unsigned short wt[64][68];   // [r][f'] bf16, padded
  const int b = blockIdx.x;
  const int tid = threadIdx.x;

  if (b < 1024) {
    // ---- adjacency compaction: one wave per row, zero barriers ----
    const int lane = tid & 63;
    const int row = b * 4 + (tid >> 6);
    const float* arow = adj + (size_t)row * NN;
    unsigned long long pm = 0;
    {
      float4 buf[8];
#pragma unroll
      for (int c = 0; c < 8; ++c)
        buf[c] = *reinterpret_cast<const float4*>(&arow[c * 256 + (lane << 2)]);
#pragma unroll
      for (int c = 0; c < 8; ++c)
        pm |= (unsigned long long)nib4(buf[c]) << (4 * c);
#pragma unroll
      for (int c = 0; c < 8; ++c)
        buf[c] = *reinterpret_cast<const float4*>(&arow[(c + 8) * 256 + (lane << 2)]);
#pragma unroll
      for (int c = 0; c < 8; ++c)
        pm |= (unsigned long long)nib4(buf[c]) << (4 * c + 32);
    }
    const int cnt = __popcll(pm);
    int pfx = cnt;
#pragma unroll
    for (int off = 1; off < 64; off <<= 1) {
      const int o = __shfl_up(pfx, off);
      if (lane >= off) pfx += o;
    }
    int pos = pfx - cnt;
    unsigned long long m = pm;
    int* cg = colsG + (size_t)row * CAP;
    while (m) {
      const int bit = (int)__builtin_ctzll(m);
      m &= m - 1;
      if (pos < CAP) cg[pos] = ((bit >> 2) << 8) + (lane << 2) + (bit & 3);
      ++pos;
    }
    const int tot = __shfl(pfx, 63);
    for (int p = tot + lane; p < CAP; p += 64) cg[p] = 0;  // pad: safe addr
    if (lane == 63) cnts[row] = tot < CAP ? tot : CAP;
  } else if (b < 3072) {
    // ---- X convert: float4 -> ushort4 ----
    const int t = (b - 1024) * 256 + tid;   // 0..524287
    const float4 v = reinterpret_cast<const float4*>(X)[t];
    ushort4 u;
    u.x = f2bf(v.x); u.y = f2bf(v.y); u.z = f2bf(v.z); u.w = f2bf(v.w);
    reinterpret_cast<ushort4*>(Xb)[t] = u;
  } else {
    // ---- W transpose-convert: block handles head h, f-tile (64f x 64r) ----
    const int b2 = b - 3072;        // 0..63
    const int h = b2 >> 3;
    const int f0 = (b2 & 7) << 6;
    const int fr = tid >> 2;        // 0..63
    const int rq = (tid & 3) << 4;  // 0,16,32,48
    const float* wp = W + (size_t)h * FF * RR + (size_t)(f0 + fr) * RR + rq;
#pragma unroll
    for (int v = 0; v < 4; ++v) {
      const float4 x = *reinterpret_cast<const float4*>(wp + v * 4);
      wt[rq + v * 4 + 0][fr] = f2bf(x.x);
      wt[rq + v * 4 + 1][fr] = f2bf(x.y);
      wt[rq + v * 4 + 2][fr] = f2bf(x.z);
      wt[rq + v * 4 + 3][fr] = f2bf(x.w);
    }
    __syncthreads();
    const int r = tid >> 2;
    unsigned short* op = BbT + (size_t)(h * 64 + r) * FF + f0 + ((tid & 3) << 4);
    int4 w0 = *reinterpret_cast<const int4*>(&wt[r][(tid & 3) << 4]);
    int4 w1 = *reinterpret_cast<const int4*>(&wt[r][((tid & 3) << 4) + 8]);
    *reinterpret_cast<int4*>(op) = w0;
    *reinterpret_cast<int4*>(op + 8) = w1;
  }
}

// ---------------------------------------------------------------------------
// K_B: hiddenT[m][n] = sum_k Xb[m][k] * BbT[n][k]  (M=4096, N=512, K=512)
// + fused epilogue: a_srcT[n][h], a_dstT[n][h] from fp32 accumulators.
// ---------------------------------------------------------------------------
__global__ __launch_bounds__(256) void k_gemm_hidden(
    const unsigned short* __restrict__ Xb,
    const unsigned short* __restrict__ BbT,
    const float* __restrict__ sa,
    unsigned short* __restrict__ hiddenT,
    float* __restrict__ a_srcT,
    float* __restrict__ a_dstT)
{
  const int row0 = blockIdx.x * 64;
  const int h = blockIdx.y;
  const int n0 = h * 64;
  __shared__ unsigned short Als[64 * 32];
  __shared__ unsigned short Bls[64 * 32];
  __shared__ float redS[64][2];
  __shared__ float redD[64][2];
  const int tid = threadIdx.x;
  const int l = tid & 63;
  const int wid = tid >> 6;
  const int wr = wid >> 1, wc = wid & 1;

  f32x4 acc[2][2];
#pragma unroll
  for (int a = 0; a < 2; ++a)
#pragma unroll
    for (int bb = 0; bb < 2; ++bb) acc[a][bb] = (f32x4){0.f, 0.f, 0.f, 0.f};

  const int srow = tid >> 2;
  const int skel = (tid & 3) * 8;

  for (int k0 = 0; k0 < FF; k0 += 32) {
    const int4 av = *reinterpret_cast<const int4*>(
        &Xb[(size_t)(row0 + srow) * FF + k0 + skel]);
    const int4 bv = *reinterpret_cast<const int4*>(
        &BbT[(size_t)(n0 + srow) * FF + k0 + skel]);
    __syncthreads();
    *reinterpret_cast<int4*>(&Als[tid * 8]) = av;
    *reinterpret_cast<int4*>(&Bls[tid * 8]) = bv;
    __syncthreads();

    const int ka = (l >> 4) * 8;
    const bf16x8 a0 = *reinterpret_cast<const bf16x8*>(&Als[(32 * wr + 0  + (l & 15)) * 32 + ka]);
    const bf16x8 a1 = *reinterpret_cast<const bf16x8*>(&Als[(32 * wr + 16 + (l & 15)) * 32 + ka]);
    const bf16x8 b0 = *reinterpret_cast<const bf16x8*>(&Bls[(32 * wc + 0  + (l & 15)) * 32 + ka]);
    const bf16x8 b1 = *reinterpret_cast<const bf16x8*>(&Bls[(32 * wc + 16 + (l & 15)) * 32 + ka]);
    acc[0][0] = __builtin_amdgcn_mfma_f32_16x16x32_bf16(a0, b0, acc[0][0], 0, 0, 0);
    acc[0][1] = __builtin_amdgcn_mfma_f32_16x16x32_bf16(a0, b1, acc[0][1], 0, 0, 0);
    acc[1][0] = __builtin_amdgcn_mfma_f32_16x16x32_bf16(a1, b0, acc[1][0], 0, 0, 0);
    acc[1][1] = __builtin_amdgcn_mfma_f32_16x16x32_bf16(a1, b1, acc[1][1], 0, 0, 0);
  }

  const int lg = l >> 4;
  const int lc = l & 15;

#pragma unroll
  for (int mi = 0; mi < 2; ++mi)
#pragma unroll
    for (int ni = 0; ni < 2; ++ni)
#pragma unroll
      for (int j = 0; j < 4; ++j) {
        const int rowg = row0 + 32 * wr + 16 * mi + (lg << 2) + j;
        const int colg = n0 + 32 * wc + 16 * ni + lc;
        hiddenT[(size_t)rowg * HR + colg] = f2bf(acc[mi][ni][j]);
      }

  float sS[2], sD[2];
#pragma unroll
  for (int ni = 0; ni < 2; ++ni) {
    const int col = 32 * wc + 16 * ni + lc;
    sS[ni] = sa[(size_t)h * 2 * RR + col];
    sD[ni] = sa[(size_t)h * 2 * RR + RR + col];
  }
#pragma unroll
  for (int mi = 0; mi < 2; ++mi)
#pragma unroll
    for (int j = 0; j < 4; ++j) {
      float ps = acc[mi][0][j] * sS[0] + acc[mi][1][j] * sS[1];
      float pd = acc[mi][0][j] * sD[0] + acc[mi][1][j] * sD[1];
#pragma unroll
      for (int off = 8; off >= 1; off >>= 1) {
        ps += __shfl_xor(ps, off);
        pd += __shfl_xor(pd, off);
      }
      if (lc == 0) {
        const int rl = 32 * wr + 16 * mi + (lg << 2) + j;
        redS[rl][wc] = ps;
        redD[rl][wc] = pd;
      }
    }
  __syncthreads();
  if (tid < 64) {
    a_srcT[(size_t)(row0 + tid) * HH + h] = redS[tid][0] + redS[tid][1];
    a_dstT[(size_t)(row0 + tid) * HH + h] = redD[tid][0] + redD[tid][1];
  }
}

// ---------------------------------------------------------------------------
// K_C: one 256-thread block per row. All gathers issued unconditionally at
// entry (colsG padded) -> no cnts dependency. 4-way split aggregation.
// ---------------------------------------------------------------------------
__global__ __launch_bounds__(256) void k_gat_row(
    const int* __restrict__ colsG,
    const int* __restrict__ cnts,
    const float* __restrict__ bias,
    const float* __restrict__ a_srcT,
    const float* __restrict__ a_dstT,
    const unsigned short* __restrict__ hiddenT,
    float* __restrict__ out)
{
  const int i = blockIdx.x;
  const int tid = threadIdx.x;

  __shared__ __align__(16) float att[HH][ATT_STRIDE];
  __shared__ int cols[CAP];
  __shared__ __align__(16) float accred[4][HR];

  // ---- all independent loads first: in flight immediately ----
  int c = 0;
  float4 d0, d1;
  float b = 0.f;
  if (tid < CAP) {
    c = colsG[(size_t)i * CAP + tid];          // padded -> always valid
  }
  const int count = cnts[i];                    // concurrent with gathers below
  if (tid < CAP) {
    b = 0.01f * bias[(size_t)i * NN + c];
    d0 = *reinterpret_cast<const float4*>(&a_dstT[(size_t)c * HH]);
    d1 = *reinterpret_cast<const float4*>(&a_dstT[(size_t)c * HH + 4]);
  }
  const float4 s0 = *reinterpret_cast<const float4*>(&a_srcT[(size_t)i * HH]);
  const float4 s1 = *reinterpret_cast<const float4*>(&a_srcT[(size_t)i * HH + 4]);

  if (tid < CAP) {
    cols[tid] = c;
    float s;
    s = s0.x + d0.x + b; att[0][tid] = (s >= 0.f) ? s : 0.2f * s;
    s = s0.y + d0.y + b; att[1][tid] = (s >= 0.f) ? s : 0.2f * s;
    s = s0.z + d0.z + b; att[2][tid] = (s >= 0.f) ? s : 0.2f * s;
    s = s0.w + d0.w + b; att[3][tid] = (s >= 0.f) ? s : 0.2f * s;
    s = s1.x + d1.x + b; att[4][tid] = (s >= 0.f) ? s : 0.2f * s;
    s = s1.y + d1.y + b; att[5][tid] = (s >= 0.f) ? s : 0.2f * s;
    s = s1.z + d1.z + b; att[6][tid] = (s >= 0.f) ? s : 0.2f * s;
    s = s1.w + d1.w + b; att[7][tid] = (s >= 0.f) ? s : 0.2f * s;
  }
  __syncthreads();

  // ---- softmax: 32-lane group g = tid>>5 owns head g ----
  {
    const int g = tid >> 5;
    const int l = tid & 31;
    float* arow_h = att[g];
    float m = -3.0e38f;
    for (int t = l; t < count; t += 32) m = fmaxf(m, arow_h[t]);
#pragma unroll
    for (int o = 16; o >= 1; o >>= 1) m = fmaxf(m, __shfl_xor(m, o));
    float ssum = 0.f;
    for (int t = l; t < count; t += 32) {
      const float e = expf(arow_h[t] - m);
      arow_h[t] = e;
      ssum += e;
    }
#pragma unroll
    for (int o = 16; o >= 1; o >>= 1) ssum += __shfl_xor(ssum, o);
    const float inv = 1.0f / ssum;
    for (int t = l; t < count; t += 32) arow_h[t] *= inv;
  }
  __syncthreads();

  // ---- aggregation: 4 groups of 64 threads; group g2 takes neighbor
  //      quarter; thread owns 8 outputs at o0 = (tid&63)*8 ----
  {
    const int g2 = tid >> 6;
    const int o0 = (tid & 63) << 3;
    const float* attrow = att[o0 >> 6];
    const unsigned short* hb = hiddenT + o0;
    const int q = (count + 3) >> 2;
    const int t0 = g2 * q;
    const int t1 = min(t0 + q, count);
    float4 accA = make_float4(0.f, 0.f, 0.f, 0.f);
    float4 accB = make_float4(0.f, 0.f, 0.f, 0.f);
    for (int t = t0; t < t1; ++t) {
      const int cc = cols[t];
      const float a = attrow[t];
      const ushort4 ua = *reinterpret_cast<const ushort4*>(hb + (size_t)cc * HR);
      const ushort4 ub = *reinterpret_cast<const ushort4*>(hb + (size_t)cc * HR + 4);
      accA.x += a * bf2f(ua.x); accA.y += a * bf2f(ua.y);
      accA.z += a * bf2f(ua.z); accA.w += a * bf2f(ua.w);
      accB.x += a * bf2f(ub.x); accB.y += a * bf2f(ub.y);
      accB.z += a * bf2f(ub.z); accB.w += a * bf2f(ub.w);
    }
    *reinterpret_cast<float4*>(&accred[g2][o0]) = accA;
    *reinterpret_cast<float4*>(&accred[g2][o0 + 4]) = accB;
  }
  __syncthreads();
  {
    const int o = tid << 1;
    const float2 r = make_float2(
        accred[0][o] + accred[1][o] + accred[2][o] + accred[3][o],
        accred[0][o + 1] + accred[1][o + 1] + accred[2][o + 1] + accred[3][o + 1]);
    *reinterpret_cast<float2*>(&out[(size_t)i * HR + o]) = r;
  }
}

extern "C" void kernel_launch(void* const* d_in, const int* in_sizes, int n_in,
                              void* d_out, int out_size, void* d_ws, size_t ws_size,
                              hipStream_t stream) {
  const float* X    = (const float*)d_in[0];   // [N,F]
  const float* adj  = (const float*)d_in[1];   // [N,N]
  const float* W    = (const float*)d_in[2];   // [H,F,R]
  const float* sa   = (const float*)d_in[3];   // [H,2R]
  const float* bias = (const float*)d_in[4];   // [N,N]
  float* out = (float*)d_out;                  // [N, H*R]

  unsigned short* hiddenT = (unsigned short*)d_ws;        // [N][512] bf16, 4 MB
  unsigned short* Xb  = hiddenT + (size_t)NN * HR;        // [N][512] bf16, 4 MB
  unsigned short* BbT = Xb + (size_t)NN * FF;             // [512][512] bf16, 512 KB
  float* a_srcT = (float*)(BbT + (size_t)HR * FF);        // [N][H], 128 KB
  float* a_dstT = a_srcT + (size_t)NN * HH;               // [N][H], 128 KB
  int* cnts     = (int*)(a_dstT + (size_t)NN * HH);       // [N], 16 KB
  int* colsG    = cnts + NN;                              // [N][CAP], 2 MB

  k_stream<<<dim3(3136), 256, 0, stream>>>(X, W, adj, Xb, BbT, colsG, cnts);
  k_gemm_hidden<<<dim3(NN / 64, HH), 256, 0, stream>>>(Xb, BbT, sa, hiddenT, a_srcT, a_dstT);
  k_gat_row<<<dim3(NN), 256, 0, stream>>>(colsG, cnts, bias, a_srcT, a_dstT, hiddenT, out);
}